// Round 9
// baseline (1066.414 us; speedup 1.0000x reference)
//
#include <hip/hip_runtime.h>

#define NROWS  50000
#define NPAIRS 25000   // NROWS / 2
#define NWAVES 1024    // 256 blocks * 4 waves

// out = x @ Wl^T + mean_k(neigh) @ Wr^T    (all fp32, D_IN = D_OUT = 128, K = 32)
__global__ __launch_bounds__(256, 1)
void sage_fused(const float* __restrict__ x,
                const float* __restrict__ neigh,
                const float* __restrict__ Wl,
                const float* __restrict__ Wr,
                float* __restrict__ out)
{
    // Wpack[dblk][j]: float4 = Wcat[j][4*dblk .. 4*dblk+3], dblk<32 -> Wl, dblk>=32 -> Wr
    // swizzled: stored at index j ^ (dblk & 7) to make staging writes cheap while
    // keeping matmul reads (consecutive j across lanes) conflict-free.
    __shared__ __align__(16) float4 Wp[64][128];          // 128 KiB
    __shared__ __align__(16) float  vbuf[4][2][256];      // per-wave, per-row [x(128) | agg(128)]

    const int t = threadIdx.x;

    // ---- stage weights (once per WG) ----
    {
        const float4* wl4 = (const float4*)Wl;
        const float4* wr4 = (const float4*)Wr;
        #pragma unroll
        for (int i = 0; i < 16; ++i) {
            int f  = i * 256 + t;        // flat quad index, 0..4095
            int j  = f >> 5;             // output row 0..127
            int db = f & 31;             // d-block 0..31
            Wp[db][j ^ (db & 7)]      = wl4[f];
            Wp[db + 32][j ^ (db & 7)] = wr4[f];
        }
    }
    __syncthreads();

    const int w  = t >> 6;               // wave in block
    const int l  = t & 63;               // lane
    const int g  = blockIdx.x * 4 + w;   // global wave id 0..1023
    const int lm = l & 31;

    float* vrow0 = vbuf[w][0];
    float* vrow1 = vbuf[w][1];
    const float4* xq4 = (const float4*)x;

    float4 bufA[16], bufB[16];
    float4 xq;

    // ---- prologue: prefetch first pair ----
    {
        const float4* ra = (const float4*)neigh + (size_t)(2 * g) * 1024 + l;
        const float4* rb = ra + 1024;
        #pragma unroll
        for (int i = 0; i < 16; ++i) bufA[i] = ra[i * 64];
        #pragma unroll
        for (int i = 0; i < 16; ++i) bufB[i] = rb[i * 64];
        xq = xq4[(size_t)(l < 32 ? 2 * g : 2 * g + 1) * 32 + lm];
    }

    for (int p = g; p < NPAIRS; p += NWAVES) {
        const int n0 = 2 * p, n1 = n0 + 1;
        const int pn = p + NWAVES;
        const bool more = pn < NPAIRS;

        // ---- reduce row A (k-sum over 32 neighbors) ----
        float4 sA;
        {
            float4 u0 = bufA[0] + bufA[1];
            float4 u1 = bufA[2] + bufA[3];
            float4 u2 = bufA[4] + bufA[5];
            float4 u3 = bufA[6] + bufA[7];
            float4 u4 = bufA[8] + bufA[9];
            float4 u5 = bufA[10] + bufA[11];
            float4 u6 = bufA[12] + bufA[13];
            float4 u7 = bufA[14] + bufA[15];
            u0 = u0 + u2; u1 = u1 + u3; u4 = u4 + u6; u5 = u5 + u7;
            u0 = u0 + u4; u1 = u1 + u5;
            sA = u0 + u1;
        }
        // refill A with next pair's row 0 (keeps HBM busy during matmul below)
        if (more) {
            const float4* ra = (const float4*)neigh + (size_t)(2 * pn) * 1024 + l;
            #pragma unroll
            for (int i = 0; i < 16; ++i) bufA[i] = ra[i * 64];
        }
        // partner-lane combine (lane l holds even/odd k-halves vs lane l^32), scale to mean
        {
            float ox = __shfl(sA.x, l ^ 32, 64);
            float oy = __shfl(sA.y, l ^ 32, 64);
            float oz = __shfl(sA.z, l ^ 32, 64);
            float ow = __shfl(sA.w, l ^ 32, 64);
            sA.x = (sA.x + ox) * 0.03125f;
            sA.y = (sA.y + oy) * 0.03125f;
            sA.z = (sA.z + oz) * 0.03125f;
            sA.w = (sA.w + ow) * 0.03125f;
            if (l < 32) *(float4*)&vrow0[128 + lm * 4] = sA;
        }

        // ---- reduce row B ----
        float4 sB;
        {
            float4 u0 = bufB[0] + bufB[1];
            float4 u1 = bufB[2] + bufB[3];
            float4 u2 = bufB[4] + bufB[5];
            float4 u3 = bufB[6] + bufB[7];
            float4 u4 = bufB[8] + bufB[9];
            float4 u5 = bufB[10] + bufB[11];
            float4 u6 = bufB[12] + bufB[13];
            float4 u7 = bufB[14] + bufB[15];
            u0 = u0 + u2; u1 = u1 + u3; u4 = u4 + u6; u5 = u5 + u7;
            u0 = u0 + u4; u1 = u1 + u5;
            sB = u0 + u1;
        }
        if (more) {
            const float4* rb = (const float4*)neigh + (size_t)(2 * pn + 1) * 1024 + l;
            #pragma unroll
            for (int i = 0; i < 16; ++i) bufB[i] = rb[i * 64];
        }
        {
            float ox = __shfl(sB.x, l ^ 32, 64);
            float oy = __shfl(sB.y, l ^ 32, 64);
            float oz = __shfl(sB.z, l ^ 32, 64);
            float ow = __shfl(sB.w, l ^ 32, 64);
            sB.x = (sB.x + ox) * 0.03125f;
            sB.y = (sB.y + oy) * 0.03125f;
            sB.z = (sB.z + oz) * 0.03125f;
            sB.w = (sB.w + ow) * 0.03125f;
            if (l < 32) *(float4*)&vrow1[128 + lm * 4] = sB;
        }

        // ---- x rows -> LDS (lanes<32: row n0, lanes>=32: row n1), refill prefetch ----
        {
            if (l < 32) *(float4*)&vrow0[lm * 4] = xq;
            else        *(float4*)&vrow1[lm * 4] = xq;
            if (more) xq = xq4[(size_t)(l < 32 ? 2 * pn : 2 * pn + 1) * 32 + lm];
        }

        // ---- matmul: out[n][j] = sum_d v[d] * Wcat[j][d], lane l does j=l and j=l+64 ----
        float acc00 = 0.f, acc01 = 0.f, acc10 = 0.f, acc11 = 0.f;
        const float4* vA = (const float4*)vrow0;
        const float4* vB = (const float4*)vrow1;
        #pragma unroll 8
        for (int db = 0; db < 64; ++db) {
            const int c = db & 7;
            float4 wa = Wp[db][(l ^ c)];
            float4 wb = Wp[db][(l ^ c) + 64];
            float4 qa = vA[db];
            float4 qb = vB[db];
            acc00 += qa.x * wa.x + qa.y * wa.y + qa.z * wa.z + qa.w * wa.w;
            acc01 += qa.x * wb.x + qa.y * wb.y + qa.z * wb.z + qa.w * wb.w;
            acc10 += qb.x * wa.x + qb.y * wa.y + qb.z * wa.z + qb.w * wa.w;
            acc11 += qb.x * wb.x + qb.y * wb.y + qb.z * wb.z + qb.w * wb.w;
        }
        out[(size_t)n0 * 128 + l]      = acc00;
        out[(size_t)n0 * 128 + 64 + l] = acc01;
        out[(size_t)n1 * 128 + l]      = acc10;
        out[(size_t)n1 * 128 + 64 + l] = acc11;
    }
}

extern "C" void kernel_launch(void* const* d_in, const int* in_sizes, int n_in,
                              void* d_out, int out_size, void* d_ws, size_t ws_size,
                              hipStream_t stream)
{
    const float* x     = (const float*)d_in[0];
    const float* neigh = (const float*)d_in[1];
    const float* Wl    = (const float*)d_in[2];
    const float* Wr    = (const float*)d_in[3];
    float* out = (float*)d_out;

    hipLaunchKernelGGL(sage_fused, dim3(256), dim3(256), 0, stream,
                       x, neigh, Wl, Wr, out);
}